// Round 4
// baseline (203.771 us; speedup 1.0000x reference)
//
#include <hip/hip_runtime.h>
#include <hip/hip_bf16.h>

// Attention: xq/xk/xv [2,2048,768] f32, W* [768,768] f32 ([out,in]), bp [768] f32.
// Pipeline: fused cast->bf16, fused QKV NT-GEMM (scale*log2e folded into Q; V
// computed TRANSPOSED via swapped operands; XCD-swizzled blocks), flash attention
// (r12 structure: r8 kv-half split, 32q/wave, K LDS-staged; V staging DROPPED --
// V fragments load global->reg issued before the barrier so L2 latency hides
// under the K-stage drain (V is L2-resident per XCD). S^T=K*Q^T, max-free
// softmax via exp2, l on MFMA pipe, in-block half-combine),
// output NT-GEMM + bias (64x96 tiles, BK=128, f32 out). LDS XOR-swizzled.

#define NSEQ 2048
#define CDIM 768
#define NH   12
#define HD   64
#define MTOT 4096            // B*NSEQ
#define XEL  (MTOT*CDIM)     // 3145728
#define WEL  (CDIM*CDIM)     // 589824
#define X8   (XEL/8)         // 393216
#define W8   (WEL/8)         // 73728
#define PSTR 72              // P row stride (shorts): 144B = 16B-aligned
#define QSCALE 0.18033688011112042f   // 0.125 * log2(e); scores consumed by exp2

typedef __attribute__((ext_vector_type(8))) short bf16x8;
typedef __attribute__((ext_vector_type(4))) float floatx4;

// scalar f32->bf16, round-half-up (2 VALU)
static __device__ __forceinline__ unsigned short f2bf(float f) {
  union { float f; unsigned int u; } v; v.f = f;
  return (unsigned short)((v.u + 0x8000u) >> 16);
}
// packed pair f32->bf16x2, round-half-up: 2 v_add + 1 v_perm
static __device__ __forceinline__ unsigned pk2bf(float a, float b) {
  unsigned ua = __float_as_uint(a) + 0x8000u;
  unsigned ub = __float_as_uint(b) + 0x8000u;
  return __builtin_amdgcn_perm(ub, ua, 0x07060302);  // {hi16(b), hi16(a)}
}

static __device__ __forceinline__ void lds16(const void* g, void* l) {
  __builtin_amdgcn_global_load_lds(
      (const __attribute__((address_space(1))) unsigned int*)g,
      (__attribute__((address_space(3))) unsigned int*)l, 16, 0, 0);
}

// ---------------- fused cast f32 -> bf16 (all 7 tensors, one launch) ----------
__global__ __launch_bounds__(256) void cast_all(
    const float* __restrict__ xq, const float* __restrict__ xk,
    const float* __restrict__ xv, const float* __restrict__ wq,
    const float* __restrict__ wk, const float* __restrict__ wv,
    const float* __restrict__ wp,
    unsigned short* __restrict__ Xq, unsigned short* __restrict__ Xk,
    unsigned short* __restrict__ Xv, unsigned short* __restrict__ Wq,
    unsigned short* __restrict__ Wk, unsigned short* __restrict__ Wv,
    unsigned short* __restrict__ Wp) {
  int i = blockIdx.x * 256 + threadIdx.x;
  const float* s; unsigned short* d; int off;
  if (i < 3 * X8) {
    int t = i / X8; off = i - t * X8;
    s = (t == 0) ? xq : (t == 1) ? xk : xv;
    d = (t == 0) ? Xq : (t == 1) ? Xk : Xv;
  } else {
    int j = i - 3 * X8; int t = j / W8; off = j - t * W8;
    s = (t == 0) ? wq : (t == 1) ? wk : (t == 2) ? wv : wp;
    d = (t == 0) ? Wq : (t == 1) ? Wk : (t == 2) ? Wv : Wp;
  }
  const float4* sp = (const float4*)s + (size_t)off * 2;
  float4 a = sp[0], b = sp[1];
  uint4 o;
  o.x = pk2bf(a.x, a.y); o.y = pk2bf(a.z, a.w);
  o.z = pk2bf(b.x, b.y); o.w = pk2bf(b.z, b.w);
  *(uint4*)(d + (size_t)off * 8) = o;
}

// ---------------- fused QKV NT-GEMM: 768 blocks, XCD-swizzled ----------------
// z=0: Q = Xq Wq^T * QSCALE, tile 128m x 96n ; z=1: K, same tiling;
// z=2: V^T = Wv Xv^T, tile 96(o) x 128(m) (coalesced Vt writes).
// Block decode: XCD (blk%8) owns 4 m-slabs x all n-tiles x all z -> A/B slabs
// mostly L2-resident per XCD.
__global__ __launch_bounds__(256) void gemm_qkv(
    const unsigned short* __restrict__ Xq, const unsigned short* __restrict__ Xk,
    const unsigned short* __restrict__ Xv, const unsigned short* __restrict__ Wq,
    const unsigned short* __restrict__ Wk, const unsigned short* __restrict__ Wv,
    unsigned short* __restrict__ Qo, unsigned short* __restrict__ Ko,
    unsigned short* __restrict__ Vo) {
  int i0 = blockIdx.x;
  int mg = i0 & 7; int t0 = i0 >> 3;       // t0 in [0,96)
  int z = t0 % 3; int u = t0 / 3;          // u in [0,32)
  int xn = u & 7, ysub = u >> 3;           // 8 n-tiles x 4 m-subtiles
  int y = mg * 4 + ysub;                   // m-tile in [0,32)
  const unsigned short* A; const unsigned short* B; int am0, bn0, RA;
  if (z == 0)      { A = Xq; B = Wq; am0 = y * 128; bn0 = xn * 96; RA = 128; }
  else if (z == 1) { A = Xk; B = Wk; am0 = y * 128; bn0 = xn * 96; RA = 128; }
  else             { A = Wv; B = Xv; am0 = xn * 96; bn0 = y * 128; RA = 96; }
  __shared__ __align__(16) unsigned short S[224 * 64];
  int tid = threadIdx.x, lane = tid & 63, wave = tid >> 6;
  int quad = lane >> 4, l15 = lane & 15, l7 = l15 & 7;

  const unsigned short* gptr[7]; int ldo[7];
#pragma unroll
  for (int i = 0; i < 7; i++) {
    int idx = i * 256 + tid;
    int row = idx >> 3, c = (idx & 7) ^ (row & 7);
    gptr[i] = (row < RA ? A + (size_t)(am0 + row) * CDIM
                        : B + (size_t)(bn0 + row - RA) * CDIM) + c * 8;
    ldo[i] = idx * 8;
  }
  floatx4 acc[12];
#pragma unroll
  for (int i = 0; i < 12; i++) acc[i] = (floatx4){0.f, 0.f, 0.f, 0.f};

  for (int k0 = 0; k0 < CDIM; k0 += 64) {
#pragma unroll
    for (int i = 0; i < 7; i++) lds16(gptr[i] + k0, &S[ldo[i]]);
    __syncthreads();
    if (z < 2) {
      int wm = (wave >> 1) * 64, wn = (wave & 1) * 48;
#pragma unroll
      for (int ks = 0; ks < 2; ks++) {
        int csw = ((ks * 4 + quad) ^ l7) * 8;
        bf16x8 af[4], bfr[3];
#pragma unroll
        for (int i = 0; i < 4; i++)
          af[i] = *(const bf16x8*)&S[(wm + i * 16 + l15) * 64 + csw];
#pragma unroll
        for (int j = 0; j < 3; j++)
          bfr[j] = *(const bf16x8*)&S[(128 + wn + j * 16 + l15) * 64 + csw];
#pragma unroll
        for (int mi = 0; mi < 4; mi++)
#pragma unroll
          for (int ni = 0; ni < 3; ni++)
            acc[mi * 3 + ni] = __builtin_amdgcn_mfma_f32_16x16x32_bf16(
                af[mi], bfr[ni], acc[mi * 3 + ni], 0, 0, 0);
      }
    } else {
      int wm = (wave & 1) * 48, wn = (wave >> 1) * 64;
#pragma unroll
      for (int ks = 0; ks < 2; ks++) {
        int csw = ((ks * 4 + quad) ^ l7) * 8;
        bf16x8 af[3], bfr[4];
#pragma unroll
        for (int i = 0; i < 3; i++)
          af[i] = *(const bf16x8*)&S[(wm + i * 16 + l15) * 64 + csw];
#pragma unroll
        for (int j = 0; j < 4; j++)
          bfr[j] = *(const bf16x8*)&S[(96 + wn + j * 16 + l15) * 64 + csw];
#pragma unroll
        for (int mi = 0; mi < 3; mi++)
#pragma unroll
          for (int ni = 0; ni < 4; ni++)
            acc[mi * 4 + ni] = __builtin_amdgcn_mfma_f32_16x16x32_bf16(
                af[mi], bfr[ni], acc[mi * 4 + ni], 0, 0, 0);
      }
    }
    __syncthreads();
  }
  if (z < 2) {
    int wm = (wave >> 1) * 64, wn = (wave & 1) * 48;
#pragma unroll
    for (int mi = 0; mi < 4; mi++)
#pragma unroll
      for (int ni = 0; ni < 3; ni++)
#pragma unroll
        for (int r = 0; r < 4; r++) {
          int grow = am0 + wm + mi * 16 + quad * 4 + r;
          int gcol = bn0 + wn + ni * 16 + l15;
          float v = acc[mi * 3 + ni][r];
          int b = grow >> 11, nq = grow & 2047, h = gcol >> 6, dd = gcol & 63;
          if (z == 0)
            Qo[((size_t)(b * NH + h) * NSEQ + nq) * HD + dd] = f2bf(v * QSCALE);
          else
            Ko[((size_t)(b * NH + h) * NSEQ + nq) * HD + dd] = f2bf(v);
        }
  } else {
    int wm = (wave & 1) * 48, wn = (wave >> 1) * 64;
#pragma unroll
    for (int mi = 0; mi < 3; mi++)
#pragma unroll
      for (int ni = 0; ni < 4; ni++)
#pragma unroll
        for (int r = 0; r < 4; r++) {
          int o = am0 + wm + mi * 16 + quad * 4 + r;
          int mgl = bn0 + wn + ni * 16 + l15;
          int b = mgl >> 11, nq = mgl & 2047;
          Vo[((size_t)b * CDIM + o) * NSEQ + nq] = f2bf(acc[mi * 4 + ni][r]);
        }
  }
}

// ---------------- flash attention: r12 = r8 minus V staging ------------------
// Q,K: [24][2048][64] bf16 (Q pre-scaled); Vt: [24][64][2048] bf16.
// ctx: [4096][768] bf16. 768 blocks x 256 thr = 4 waves:
//   wave = (half<<1)|qsub: qsub selects 32 q-rows, half selects kv range.
// K staged to LDS via global_load_lds (XOR-swizzled). V is NOT staged: the 8
// V fragments load global->reg, issued BEFORE __syncthreads so their L2
// latency completes during the barrier's vmcnt drain of the K staging (V is
// L2-resident per XCD thanks to the blk%8 head swizzle). This halves the
// staging drain, removes 8/16 per-wave ds_reads from the LDS pipe, and cuts
// LDS to 25.6 KB. l accumulated on the MFMA pipe (ones-fragment). Max-free
// softmax => kv-partials combine exactly through LDS.
__global__ __launch_bounds__(256, 3) void attn_kernel(
    const unsigned short* __restrict__ Q, const unsigned short* __restrict__ K,
    const unsigned short* __restrict__ Vt, unsigned short* __restrict__ ctx) {
  int i0 = blockIdx.x;
  int xcd = i0 & 7; int t0 = i0 >> 3;
  int bh = xcd * 3 + (t0 >> 5);
  int qt = t0 & 31;
  int tid = threadIdx.x, lane = tid & 63, wave = tid >> 6;
  int half = wave >> 1, qsub = wave & 1;
  int quad = lane >> 4, l15 = lane & 15, l7 = l15 & 7;
  __shared__ __align__(16) unsigned short Ks[2][64 * 64];
  __shared__ __align__(16) unsigned short Ps[4][16 * PSTR];

  const unsigned short* Qg = Q + ((size_t)bh * NSEQ + qt * 64 + qsub * 32) * HD;
  const unsigned short* Kg = K + ((size_t)bh * NSEQ + half * 1024) * HD;
  const unsigned short* Vg = Vt + (size_t)bh * HD * NSEQ + half * 1024;

  bf16x8 qf[2][2];
#pragma unroll
  for (int qi = 0; qi < 2; qi++)
#pragma unroll
    for (int ks = 0; ks < 2; ks++)
      qf[qi][ks] = *(const bf16x8*)(Qg + (qi * 16 + l15) * HD + ks * 32 + quad * 8);

  bf16x8 ones;
#pragma unroll
  for (int i = 0; i < 8; i++) ones[i] = (short)0x3F80;  // bf16 1.0

  // K staging: each half's 128 threads stage that half's 8KB K-tile
  int tid2 = tid & 127;
  int kgo[4], ldst[4];
#pragma unroll
  for (int i = 0; i < 4; i++) {
    int idx = i * 128 + tid2;
    int R = idx >> 3, c = (idx & 7) ^ (R & 7);
    kgo[i] = R * HD + c * 8;
    ldst[i] = idx * 8;
  }
  unsigned short* Ksh = Ks[half];
  unsigned short* Pw = &Ps[wave][0];

  // V direct-load row pointers: fragment (dt,x) of tile t reads
  //   Vt[dt*16+l15][t*64 + (x*4+quad)*8 .. +8]  (identical bytes to the old
  //   staged+XOR-swizzled LDS read -- the swizzle was a net identity)
  const unsigned short* vp[4];
#pragma unroll
  for (int dt = 0; dt < 4; dt++)
    vp[dt] = Vg + (size_t)(dt * 16 + l15) * NSEQ + quad * 8;

  floatx4 ol[2];
  floatx4 o[2][4];
#pragma unroll
  for (int qi = 0; qi < 2; qi++) {
    ol[qi] = (floatx4){0.f, 0.f, 0.f, 0.f};
#pragma unroll
    for (int dt = 0; dt < 4; dt++) o[qi][dt] = (floatx4){0.f, 0.f, 0.f, 0.f};
  }

  for (int t = 0; t < 16; t++) {
    int k0 = t * 64;
#pragma unroll
    for (int i = 0; i < 4; i++)
      lds16(Kg + (size_t)k0 * HD + kgo[i], &Ksh[ldst[i]]);
    // V fragment loads issued alongside K staging; completed by the barrier's
    // vmcnt drain, consumed ~400 cycles later in PV.
    bf16x8 vf[4][2];
#pragma unroll
    for (int dt = 0; dt < 4; dt++)
#pragma unroll
      for (int x = 0; x < 2; x++)
        vf[dt][x] = *(const bf16x8*)(vp[dt] + k0 + x * 32);
    __syncthreads();

    bf16x8 kf[4][2];
#pragma unroll
    for (int nt = 0; nt < 4; nt++)
#pragma unroll
      for (int x = 0; x < 2; x++)
        kf[nt][x] = *(const bf16x8*)&Ksh[(nt * 16 + l15) * 64 + ((x * 4 + quad) ^ l7) * 8];

#pragma unroll
    for (int qi = 0; qi < 2; qi++) {
      // S^T = K Q^T: rows kv=nt*16+quad*4+r, col q=l15
#pragma unroll
      for (int nt = 0; nt < 4; nt++) {
        floatx4 st = (floatx4){0.f, 0.f, 0.f, 0.f};
        st = __builtin_amdgcn_mfma_f32_16x16x32_bf16(kf[nt][0], qf[qi][0], st, 0, 0, 0);
        st = __builtin_amdgcn_mfma_f32_16x16x32_bf16(kf[nt][1], qf[qi][1], st, 0, 0, 0);
        float p0 = __builtin_exp2f(st[0]), p1 = __builtin_exp2f(st[1]);
        float p2 = __builtin_exp2f(st[2]), p3 = __builtin_exp2f(st[3]);
        *(uint2*)&Pw[l15 * PSTR + nt * 16 + quad * 4] =
            make_uint2(pk2bf(p0, p1), pk2bf(p2, p3));
      }
      // O^T += Vt P^T; l += ones x P (matrix pipe)
#pragma unroll
      for (int ks = 0; ks < 2; ks++) {
        bf16x8 pf = *(const bf16x8*)&Pw[l15 * PSTR + ks * 32 + quad * 8];
        ol[qi] = __builtin_amdgcn_mfma_f32_16x16x32_bf16(ones, pf, ol[qi], 0, 0, 0);
#pragma unroll
        for (int dt = 0; dt < 4; dt++)
          o[qi][dt] = __builtin_amdgcn_mfma_f32_16x16x32_bf16(vf[dt][ks], pf, o[qi][dt], 0, 0, 0);
      }
    }
    __syncthreads();
  }
  // in-block kv-partial combine: half-1 -> LDS, half-0 adds + stores
  float* Obuf = (float*)&Ks[0][0];   // 64q x 64d f32 = 16 KB (Ks is exactly 16 KB)
  float* Lbuf = (float*)&Ps[0][0];   // 64 floats
  if (half == 1) {
#pragma unroll
    for (int qi = 0; qi < 2; qi++) {
      int ro = qsub * 32 + qi * 16 + l15;
#pragma unroll
      for (int dt = 0; dt < 4; dt++)
        *(floatx4*)&Obuf[ro * 64 + dt * 16 + quad * 4] = o[qi][dt];
      if (quad == 0) Lbuf[ro] = ol[qi][0];
    }
  }
  __syncthreads();
  if (half == 0) {
    int b = bh / NH, h = bh - b * NH;
#pragma unroll
    for (int qi = 0; qi < 2; qi++) {
      int ro = qsub * 32 + qi * 16 + l15;
      float inv = 1.f / (ol[qi][0] + Lbuf[ro]);
      int qrow = qt * 64 + ro;
      size_t gbase = (size_t)(b * NSEQ + qrow) * CDIM + h * HD + quad * 4;
#pragma unroll
      for (int dt = 0; dt < 4; dt++) {
        floatx4 ob = *(floatx4*)&Obuf[ro * 64 + dt * 16 + quad * 4];
        float v0 = (o[qi][dt][0] + ob[0]) * inv, v1 = (o[qi][dt][1] + ob[1]) * inv;
        float v2 = (o[qi][dt][2] + ob[2]) * inv, v3 = (o[qi][dt][3] + ob[3]) * inv;
        *(uint2*)&ctx[gbase + dt * 16] = make_uint2(pk2bf(v0, v1), pk2bf(v2, v3));
      }
    }
  }
}

// ------------- output NT-GEMM + bias, 64x96 tiles, BK=128, XCD-swizzled ------
__global__ __launch_bounds__(256) void gemm_out(
    const unsigned short* __restrict__ A, const unsigned short* __restrict__ B,
    const float* __restrict__ bias, float* __restrict__ out) {
  int i0 = blockIdx.x;                  // 512 blocks = 2/CU
  int mg = i0 & 7; int t0 = i0 >> 3;    // t0 in [0,64)
  int n0 = (t0 & 7) * 96;
  int m0 = (mg * 8 + (t0 >> 3)) * 64;
  __shared__ __align__(16) unsigned short S[160 * 128];  // A rows 0..63, B rows 64..159
  int tid = threadIdx.x, lane = tid & 63, wave = tid >> 6;
  int quad = lane >> 4, l15 = lane & 15, l7 = l15 & 7;
  int wm = (wave >> 1) * 32, wn = (wave & 1) * 48;
  floatx4 acc[6];
#pragma unroll
  for (int i = 0; i < 6; i++) acc[i] = (floatx4){0.f, 0.f, 0.f, 0.f};

  for (int k0 = 0; k0 < CDIM; k0 += 128) {
#pragma unroll
    for (int i = 0; i < 10; i++) {       // 160 rows x 16 chunks = 2560 = 10*256
      int idx = i * 256 + tid;
      int R = idx >> 4, c4 = idx & 15;
      int cs = (c4 & 8) | ((c4 & 7) ^ (R & 7));
      const unsigned short* g = (R < 64)
          ? A + (size_t)(m0 + R) * CDIM : B + (size_t)(n0 + R - 64) * CDIM;
      lds16(g + k0 + cs * 8, &S[idx * 8]);
    }
    __syncthreads();
#pragma unroll
    for (int ks = 0; ks < 4; ks++) {
      int c = ks * 4 + quad;
      int csw = ((c & 8) | ((c & 7) ^ l7)) * 8;
      bf16x8 af[2], bfr[3];
#pragma unroll
      for (int i = 0; i < 2; i++)
        af[i] = *(const bf16x8*)&S[(wm + i * 16 + l15) * 128 + csw];
#pragma unroll
      for (int j = 0; j < 3; j++)
        bfr[j] = *(const bf16x8*)&S[(64 + wn + j * 16 + l15) * 128 + csw];
#pragma unroll
      for (int mi = 0; mi < 2; mi++)
#pragma unroll
        for (int ni = 0; ni < 3; ni++)
          acc[mi * 3 + ni] = __builtin_amdgcn_mfma_f32_16x16x32_bf16(
              af[mi], bfr[ni], acc[mi * 3 + ni], 0, 0, 0);
    }
    __syncthreads();
  }
  float bv[3];
#pragma unroll
  for (int ni = 0; ni < 3; ni++) bv[ni] = bias[n0 + wn + ni * 16 + l15];
#pragma unroll
  for (int mi = 0; mi < 2; mi++)
#pragma unroll
    for (int ni = 0; ni < 3; ni++)
#pragma unroll
      for (int r = 0; r < 4; r++) {
        int grow = m0 + wm + mi * 16 + quad * 4 + r;
        int gcol = n0 + wn + ni * 16 + l15;
        out[(size_t)grow * CDIM + gcol] = acc[mi * 3 + ni][r] + bv[ni];
      }
}

extern "C" void kernel_launch(void* const* d_in, const int* in_sizes, int n_in,
                              void* d_out, int out_size, void* d_ws, size_t ws_size,
                              hipStream_t stream) {
  const float* xq = (const float*)d_in[0];
  const float* xk = (const float*)d_in[1];
  const float* xv = (const float*)d_in[2];
  const float* wq = (const float*)d_in[3];
  const float* wk = (const float*)d_in[4];
  const float* wv = (const float*)d_in[5];
  const float* wp = (const float*)d_in[6];
  const float* bp = (const float*)d_in[7];
  float* out = (float*)d_out;

  char* p = (char*)d_ws;
  unsigned short* Xq = (unsigned short*)p; p += (size_t)XEL * 2;
  unsigned short* Xk = (unsigned short*)p; p += (size_t)XEL * 2;
  unsigned short* Xv = (unsigned short*)p; p += (size_t)XEL * 2;
  unsigned short* Wq = (unsigned short*)p; p += (size_t)WEL * 2;
  unsigned short* Wk = (unsigned short*)p; p += (size_t)WEL * 2;
  unsigned short* Wv = (unsigned short*)p; p += (size_t)WEL * 2;
  unsigned short* Wp = (unsigned short*)p; p += (size_t)WEL * 2;
  unsigned short* Qb = (unsigned short*)p; p += (size_t)XEL * 2;
  unsigned short* Kb = (unsigned short*)p; p += (size_t)XEL * 2;
  unsigned short* Vb = (unsigned short*)p; p += (size_t)XEL * 2;
  unsigned short* Cx = (unsigned short*)p; p += (size_t)XEL * 2;

  cast_all<<<(3 * X8 + 4 * W8) / 256, 256, 0, stream>>>(
      xq, xk, xv, wq, wk, wv, wp, Xq, Xk, Xv, Wq, Wk, Wv, Wp);

  gemm_qkv<<<768, 256, 0, stream>>>(
      Xq, Xk, Xv, Wq, Wk, Wv, Qb, Kb, Vb);

  attn_kernel<<<768, 256, 0, stream>>>(Qb, Kb, Vb, Cx);

  gemm_out<<<512, 256, 0, stream>>>(Cx, Wp, bp, out);
}

// Round 5
// 186.073 us; speedup vs baseline: 1.0951x; 1.0951x over previous
//
#include <hip/hip_runtime.h>
#include <hip/hip_bf16.h>

// Attention: xq/xk/xv [2,2048,768] f32, W* [768,768] f32 ([out,in]), bp [768] f32.
// Pipeline: fused cast->bf16, fused QKV NT-GEMM (scale*log2e folded into Q; V
// computed TRANSPOSED via swapped operands; XCD-swizzled blocks), flash attention
// (r13 structure: 32x32x16 MFMA, P ENTIRELY IN REGISTERS -- swapped S^T=K*Q^T
// puts 16 kv-scores per lane for one q; max-free softmax needs no row reduce;
// repack to PV B-operand via v_permlane32_swap_b32 (2 per 16-kv fragment).
// No Ps LDS buffer, no P ds_write/ds_read, l via VALU tree + one permlane.
// K/V LDS-staged per kv-half exactly as r8 (proven); in-block half-combine),
// output NT-GEMM + bias (64x96 tiles, BK=128, f32 out). LDS XOR-swizzled.

#define NSEQ 2048
#define CDIM 768
#define NH   12
#define HD   64
#define MTOT 4096            // B*NSEQ
#define XEL  (MTOT*CDIM)     // 3145728
#define WEL  (CDIM*CDIM)     // 589824
#define X8   (XEL/8)         // 393216
#define W8   (WEL/8)         // 73728
#define QSCALE 0.18033688011112042f   // 0.125 * log2(e); scores consumed by exp2

typedef __attribute__((ext_vector_type(8))) short bf16x8;
typedef __attribute__((ext_vector_type(4))) float floatx4;
typedef __attribute__((ext_vector_type(16))) float floatx16;
typedef __attribute__((ext_vector_type(4))) unsigned int uintx4;

// scalar f32->bf16, round-half-up (2 VALU)
static __device__ __forceinline__ unsigned short f2bf(float f) {
  union { float f; unsigned int u; } v; v.f = f;
  return (unsigned short)((v.u + 0x8000u) >> 16);
}
// packed pair f32->bf16x2, round-half-up: 2 v_add + 1 v_perm
static __device__ __forceinline__ unsigned pk2bf(float a, float b) {
  unsigned ua = __float_as_uint(a) + 0x8000u;
  unsigned ub = __float_as_uint(b) + 0x8000u;
  return __builtin_amdgcn_perm(ub, ua, 0x07060302);  // {hi16(b), hi16(a)}
}

static __device__ __forceinline__ void lds16(const void* g, void* l) {
  __builtin_amdgcn_global_load_lds(
      (const __attribute__((address_space(1))) unsigned int*)g,
      (__attribute__((address_space(3))) unsigned int*)l, 16, 0, 0);
}

// ---------------- fused cast f32 -> bf16 (all 7 tensors, one launch) ----------
__global__ __launch_bounds__(256) void cast_all(
    const float* __restrict__ xq, const float* __restrict__ xk,
    const float* __restrict__ xv, const float* __restrict__ wq,
    const float* __restrict__ wk, const float* __restrict__ wv,
    const float* __restrict__ wp,
    unsigned short* __restrict__ Xq, unsigned short* __restrict__ Xk,
    unsigned short* __restrict__ Xv, unsigned short* __restrict__ Wq,
    unsigned short* __restrict__ Wk, unsigned short* __restrict__ Wv,
    unsigned short* __restrict__ Wp) {
  int i = blockIdx.x * 256 + threadIdx.x;
  const float* s; unsigned short* d; int off;
  if (i < 3 * X8) {
    int t = i / X8; off = i - t * X8;
    s = (t == 0) ? xq : (t == 1) ? xk : xv;
    d = (t == 0) ? Xq : (t == 1) ? Xk : Xv;
  } else {
    int j = i - 3 * X8; int t = j / W8; off = j - t * W8;
    s = (t == 0) ? wq : (t == 1) ? wk : (t == 2) ? wv : wp;
    d = (t == 0) ? Wq : (t == 1) ? Wk : (t == 2) ? Wv : Wp;
  }
  const float4* sp = (const float4*)s + (size_t)off * 2;
  float4 a = sp[0], b = sp[1];
  uint4 o;
  o.x = pk2bf(a.x, a.y); o.y = pk2bf(a.z, a.w);
  o.z = pk2bf(b.x, b.y); o.w = pk2bf(b.z, b.w);
  *(uint4*)(d + (size_t)off * 8) = o;
}

// ---------------- fused QKV NT-GEMM: 768 blocks, XCD-swizzled ----------------
__global__ __launch_bounds__(256) void gemm_qkv(
    const unsigned short* __restrict__ Xq, const unsigned short* __restrict__ Xk,
    const unsigned short* __restrict__ Xv, const unsigned short* __restrict__ Wq,
    const unsigned short* __restrict__ Wk, const unsigned short* __restrict__ Wv,
    unsigned short* __restrict__ Qo, unsigned short* __restrict__ Ko,
    unsigned short* __restrict__ Vo) {
  int i0 = blockIdx.x;
  int mg = i0 & 7; int t0 = i0 >> 3;       // t0 in [0,96)
  int z = t0 % 3; int u = t0 / 3;          // u in [0,32)
  int xn = u & 7, ysub = u >> 3;           // 8 n-tiles x 4 m-subtiles
  int y = mg * 4 + ysub;                   // m-tile in [0,32)
  const unsigned short* A; const unsigned short* B; int am0, bn0, RA;
  if (z == 0)      { A = Xq; B = Wq; am0 = y * 128; bn0 = xn * 96; RA = 128; }
  else if (z == 1) { A = Xk; B = Wk; am0 = y * 128; bn0 = xn * 96; RA = 128; }
  else             { A = Wv; B = Xv; am0 = xn * 96; bn0 = y * 128; RA = 96; }
  __shared__ __align__(16) unsigned short S[224 * 64];
  int tid = threadIdx.x, lane = tid & 63, wave = tid >> 6;
  int quad = lane >> 4, l15 = lane & 15, l7 = l15 & 7;

  const unsigned short* gptr[7]; int ldo[7];
#pragma unroll
  for (int i = 0; i < 7; i++) {
    int idx = i * 256 + tid;
    int row = idx >> 3, c = (idx & 7) ^ (row & 7);
    gptr[i] = (row < RA ? A + (size_t)(am0 + row) * CDIM
                        : B + (size_t)(bn0 + row - RA) * CDIM) + c * 8;
    ldo[i] = idx * 8;
  }
  floatx4 acc[12];
#pragma unroll
  for (int i = 0; i < 12; i++) acc[i] = (floatx4){0.f, 0.f, 0.f, 0.f};

  for (int k0 = 0; k0 < CDIM; k0 += 64) {
#pragma unroll
    for (int i = 0; i < 7; i++) lds16(gptr[i] + k0, &S[ldo[i]]);
    __syncthreads();
    if (z < 2) {
      int wm = (wave >> 1) * 64, wn = (wave & 1) * 48;
#pragma unroll
      for (int ks = 0; ks < 2; ks++) {
        int csw = ((ks * 4 + quad) ^ l7) * 8;
        bf16x8 af[4], bfr[3];
#pragma unroll
        for (int i = 0; i < 4; i++)
          af[i] = *(const bf16x8*)&S[(wm + i * 16 + l15) * 64 + csw];
#pragma unroll
        for (int j = 0; j < 3; j++)
          bfr[j] = *(const bf16x8*)&S[(128 + wn + j * 16 + l15) * 64 + csw];
#pragma unroll
        for (int mi = 0; mi < 4; mi++)
#pragma unroll
          for (int ni = 0; ni < 3; ni++)
            acc[mi * 3 + ni] = __builtin_amdgcn_mfma_f32_16x16x32_bf16(
                af[mi], bfr[ni], acc[mi * 3 + ni], 0, 0, 0);
      }
    } else {
      int wm = (wave & 1) * 48, wn = (wave >> 1) * 64;
#pragma unroll
      for (int ks = 0; ks < 2; ks++) {
        int csw = ((ks * 4 + quad) ^ l7) * 8;
        bf16x8 af[3], bfr[4];
#pragma unroll
        for (int i = 0; i < 3; i++)
          af[i] = *(const bf16x8*)&S[(wm + i * 16 + l15) * 64 + csw];
#pragma unroll
        for (int j = 0; j < 4; j++)
          bfr[j] = *(const bf16x8*)&S[(96 + wn + j * 16 + l15) * 64 + csw];
#pragma unroll
        for (int mi = 0; mi < 3; mi++)
#pragma unroll
          for (int ni = 0; ni < 4; ni++)
            acc[mi * 4 + ni] = __builtin_amdgcn_mfma_f32_16x16x32_bf16(
                af[mi], bfr[ni], acc[mi * 4 + ni], 0, 0, 0);
      }
    }
    __syncthreads();
  }
  if (z < 2) {
    int wm = (wave >> 1) * 64, wn = (wave & 1) * 48;
#pragma unroll
    for (int mi = 0; mi < 4; mi++)
#pragma unroll
      for (int ni = 0; ni < 3; ni++)
#pragma unroll
        for (int r = 0; r < 4; r++) {
          int grow = am0 + wm + mi * 16 + quad * 4 + r;
          int gcol = bn0 + wn + ni * 16 + l15;
          float v = acc[mi * 3 + ni][r];
          int b = grow >> 11, nq = grow & 2047, h = gcol >> 6, dd = gcol & 63;
          if (z == 0)
            Qo[((size_t)(b * NH + h) * NSEQ + nq) * HD + dd] = f2bf(v * QSCALE);
          else
            Ko[((size_t)(b * NH + h) * NSEQ + nq) * HD + dd] = f2bf(v);
        }
  } else {
    int wm = (wave & 1) * 48, wn = (wave >> 1) * 64;
#pragma unroll
    for (int mi = 0; mi < 3; mi++)
#pragma unroll
      for (int ni = 0; ni < 4; ni++)
#pragma unroll
        for (int r = 0; r < 4; r++) {
          int o = am0 + wm + mi * 16 + quad * 4 + r;
          int mgl = bn0 + wn + ni * 16 + l15;
          int b = mgl >> 11, nq = mgl & 2047;
          Vo[((size_t)b * CDIM + o) * NSEQ + nq] = f2bf(acc[mi * 4 + ni][r]);
        }
  }
}

// ---------------- flash attention: r13 32x32 MFMA, in-register P -------------
// Q,K: [24][2048][64] bf16 (Q pre-scaled); Vt: [24][64][2048] bf16.
// ctx: [4096][768] bf16. 768 blocks x 256 thr = 4 waves:
//   wave = (half<<1)|qsub: qsub selects 32 q-rows, half selects kv half (1024).
// Per 64-kv tile per wave: 2 kvblk of 32:
//   S^T[kv32][q32] = K*Q^T via 4 chained mfma_32x32x16 (d=64).
//   Lane holds 16 scores for q=lane&31: kv = (r&3)+8*(r>>2)+4*(lane>>5).
//   exp2 -> pack pairs (pk2bf) -> v_permlane32_swap_b32 x4 -> two PV B-fragments
//   (k=(lane>>5)*8+j layout) -- P NEVER touches LDS.
//   PV: O^T[d][q] += Vt*P^T, 2 dt x 2 kvsub mfma; l = VALU tree sum per lane
//   (covers lane's half; one final permlane swap completes it).
// K/V staged to LDS exactly as r8 (XOR-swizzled, per-half tiles, 2 barriers).
// Max-free softmax => halves combine exactly through LDS (swizzled Obuf).
__global__ __launch_bounds__(256, 3) void attn_kernel(
    const unsigned short* __restrict__ Q, const unsigned short* __restrict__ K,
    const unsigned short* __restrict__ Vt, unsigned short* __restrict__ ctx) {
  int i0 = blockIdx.x;
  int xcd = i0 & 7; int t0 = i0 >> 3;
  int bh = xcd * 3 + (t0 >> 5);
  int qt = t0 & 31;
  int tid = threadIdx.x, lane = tid & 63, wave = tid >> 6;
  int half = wave >> 1, qsub = wave & 1;
  int l31 = lane & 31, hi = lane >> 5;
  __shared__ __align__(16) unsigned short Ks[2][64 * 64];
  __shared__ __align__(16) unsigned short Vs[2][64 * 64];
  __shared__ float Lbuf[64];

  const unsigned short* Qg = Q + ((size_t)bh * NSEQ + qt * 64 + qsub * 32) * HD;
  const unsigned short* Kg = K + ((size_t)bh * NSEQ + half * 1024) * HD;
  const unsigned short* Vg = Vt + (size_t)bh * HD * NSEQ + half * 1024;

  // Q fragments (B-operand): lane holds Q[q=l31][d = dchunk*16 + hi*8 + j]
  bf16x8 qf[4];
#pragma unroll
  for (int dc = 0; dc < 4; dc++)
    qf[dc] = *(const bf16x8*)(Qg + l31 * HD + dc * 16 + hi * 8);

  // K/V staging (r8-identical): each half's 128 threads stage 8KB K + 8KB V
  int tid2 = tid & 127;
  int kgo[4], vgo[4], ldst[4];
#pragma unroll
  for (int i = 0; i < 4; i++) {
    int idx = i * 128 + tid2;
    int R = idx >> 3, c = (idx & 7) ^ (R & 7);
    kgo[i] = R * HD + c * 8;
    vgo[i] = R * NSEQ + c * 8;
    ldst[i] = idx * 8;
  }
  unsigned short* Ksh = Ks[half];
  unsigned short* Vsh = Vs[half];

  floatx16 o[2];
#pragma unroll
  for (int dt = 0; dt < 2; dt++) o[dt] = (floatx16)(0.f);
  float l_acc = 0.f;

  for (int t = 0; t < 16; t++) {
    int k0 = t * 64;
#pragma unroll
    for (int i = 0; i < 4; i++) {
      lds16(Kg + (size_t)k0 * HD + kgo[i], &Ksh[ldst[i]]);
      lds16(Vg + k0 + vgo[i], &Vsh[ldst[i]]);
    }
    __syncthreads();

    // K fragments (A): row kv = kvblk*32 + l31, k = dc*16 + hi*8 + j
    bf16x8 kf[2][4];
#pragma unroll
    for (int kb = 0; kb < 2; kb++)
#pragma unroll
      for (int dc = 0; dc < 4; dc++) {
        int R = kb * 32 + l31, c = dc * 2 + hi;
        kf[kb][dc] = *(const bf16x8*)&Ksh[R * 64 + ((c ^ (R & 7)) * 8)];
      }
    // V fragments (A): row d = dt*32 + l31, k(kv) = kb*32 + kvs*16 + hi*8 + j
    bf16x8 vf[2][4];
#pragma unroll
    for (int dt = 0; dt < 2; dt++)
#pragma unroll
      for (int j = 0; j < 4; j++) {
        int R = dt * 32 + l31, c = j * 2 + hi;
        vf[dt][j] = *(const bf16x8*)&Vsh[R * 64 + ((c ^ (R & 7)) * 8)];
      }

#pragma unroll
    for (int kb = 0; kb < 2; kb++) {
      floatx16 st = (floatx16)(0.f);
#pragma unroll
      for (int dc = 0; dc < 4; dc++)
        st = __builtin_amdgcn_mfma_f32_32x32x16_bf16(kf[kb][dc], qf[dc], st, 0, 0, 0);
      // exp2 all 16 scores (max-free softmax)
      float p[16];
#pragma unroll
      for (int r = 0; r < 16; r++) p[r] = __builtin_exp2f(st[r]);
      // l: VALU tree sum of this lane's 16 values
      l_acc += ((p[0] + p[1]) + (p[2] + p[3])) + ((p[4] + p[5]) + (p[6] + p[7])) +
               (((p[8] + p[9]) + (p[10] + p[11])) + ((p[12] + p[13]) + (p[14] + p[15])));
      // pack pairs: w[i] = bf16{p[2i], p[2i+1]}, kv = pair base + 4*hi
      unsigned w[8];
#pragma unroll
      for (int i = 0; i < 8; i++) w[i] = pk2bf(p[2 * i], p[2 * i + 1]);
      // permlane32_swap: build PV B-fragments (k = hi*8 + j within each kv16)
      // swap(a,b): a' = {a_lo, b_lo}, b' = {a_hi, b_hi}
#pragma unroll
      for (int kvs = 0; kvs < 2; kvs++) {
        unsigned a0 = w[kvs * 4 + 0], b0 = w[kvs * 4 + 2];
        unsigned a1 = w[kvs * 4 + 1], b1 = w[kvs * 4 + 3];
        asm volatile("v_permlane32_swap_b32 %0, %1" : "+v"(a0), "+v"(b0));
        asm volatile("v_permlane32_swap_b32 %0, %1" : "+v"(a1), "+v"(b1));
        uintx4 pw; pw[0] = a0; pw[1] = a1; pw[2] = b0; pw[3] = b1;
        bf16x8 pb = *(bf16x8*)&pw;
#pragma unroll
        for (int dt = 0; dt < 2; dt++)
          o[dt] = __builtin_amdgcn_mfma_f32_32x32x16_bf16(
              vf[dt][kb * 2 + kvs], pb, o[dt], 0, 0, 0);
      }
    }
    __syncthreads();
  }

  // complete l across lane halves: one permlane swap + add
  unsigned lu = __float_as_uint(l_acc), lv = __float_as_uint(l_acc);
  asm volatile("v_permlane32_swap_b32 %0, %1" : "+v"(lu), "+v"(lv));
  float lfull = __uint_as_float(lu) + __uint_as_float(lv);

  // in-block kv-half combine: half-1 -> LDS, half-0 adds + stores.
  // Obuf chunks XOR-swizzled by q (linear [64q][64d] f32 would be 32-way).
  float* Obuf = (float*)&Ks[0][0];   // 64q x 64d f32 = 16 KB (== Ks)
  int q = qsub * 32 + l31;
  if (half == 1) {
#pragma unroll
    for (int dt = 0; dt < 2; dt++)
#pragma unroll
      for (int rq = 0; rq < 4; rq++) {
        int ch = (dt * 8 + rq * 2 + hi) ^ (l31 & 15);
        floatx4 v4 = {o[dt][rq * 4 + 0], o[dt][rq * 4 + 1],
                      o[dt][rq * 4 + 2], o[dt][rq * 4 + 3]};
        *(floatx4*)&Obuf[q * 64 + ch * 4] = v4;
      }
    if (lane < 32) Lbuf[qsub * 32 + lane] = lfull;
  }
  __syncthreads();
  if (half == 0) {
    int b = bh / NH, h = bh - b * NH;
    float inv = 1.f / (lfull + Lbuf[q]);
    int qrow = qt * 64 + q;
#pragma unroll
    for (int dt = 0; dt < 2; dt++)
#pragma unroll
      for (int rq = 0; rq < 4; rq++) {
        int ch = (dt * 8 + rq * 2 + hi) ^ (l31 & 15);
        floatx4 ob = *(floatx4*)&Obuf[q * 64 + ch * 4];
        float v0 = (o[dt][rq * 4 + 0] + ob[0]) * inv;
        float v1 = (o[dt][rq * 4 + 1] + ob[1]) * inv;
        float v2 = (o[dt][rq * 4 + 2] + ob[2]) * inv;
        float v3 = (o[dt][rq * 4 + 3] + ob[3]) * inv;
        size_t gbase = (size_t)(b * NSEQ + qrow) * CDIM + h * HD +
                       dt * 32 + rq * 8 + hi * 4;
        *(uint2*)&ctx[gbase] = make_uint2(pk2bf(v0, v1), pk2bf(v2, v3));
      }
  }
}

// ------------- output NT-GEMM + bias, 64x96 tiles, BK=128, XCD-swizzled ------
__global__ __launch_bounds__(256) void gemm_out(
    const unsigned short* __restrict__ A, const unsigned short* __restrict__ B,
    const float* __restrict__ bias, float* __restrict__ out) {
  int i0 = blockIdx.x;                  // 512 blocks = 2/CU
  int mg = i0 & 7; int t0 = i0 >> 3;    // t0 in [0,64)
  int n0 = (t0 & 7) * 96;
  int m0 = (mg * 8 + (t0 >> 3)) * 64;
  __shared__ __align__(16) unsigned short S[160 * 128];  // A rows 0..63, B rows 64..159
  int tid = threadIdx.x, lane = tid & 63, wave = tid >> 6;
  int quad = lane >> 4, l15 = lane & 15, l7 = l15 & 7;
  int wm = (wave >> 1) * 32, wn = (wave & 1) * 48;
  floatx4 acc[6];
#pragma unroll
  for (int i = 0; i < 6; i++) acc[i] = (floatx4){0.f, 0.f, 0.f, 0.f};

  for (int k0 = 0; k0 < CDIM; k0 += 128) {
#pragma unroll
    for (int i = 0; i < 10; i++) {       // 160 rows x 16 chunks = 2560 = 10*256
      int idx = i * 256 + tid;
      int R = idx >> 4, c4 = idx & 15;
      int cs = (c4 & 8) | ((c4 & 7) ^ (R & 7));
      const unsigned short* g = (R < 64)
          ? A + (size_t)(m0 + R) * CDIM : B + (size_t)(n0 + R - 64) * CDIM;
      lds16(g + k0 + cs * 8, &S[idx * 8]);
    }
    __syncthreads();
#pragma unroll
    for (int ks = 0; ks < 4; ks++) {
      int c = ks * 4 + quad;
      int csw = ((c & 8) | ((c & 7) ^ l7)) * 8;
      bf16x8 af[2], bfr[3];
#pragma unroll
      for (int i = 0; i < 2; i++)
        af[i] = *(const bf16x8*)&S[(wm + i * 16 + l15) * 128 + csw];
#pragma unroll
      for (int j = 0; j < 3; j++)
        bfr[j] = *(const bf16x8*)&S[(64 + wn + j * 16 + l15) * 128 + csw];
#pragma unroll
      for (int mi = 0; mi < 2; mi++)
#pragma unroll
        for (int ni = 0; ni < 3; ni++)
          acc[mi * 3 + ni] = __builtin_amdgcn_mfma_f32_16x16x32_bf16(
              af[mi], bfr[ni], acc[mi * 3 + ni], 0, 0, 0);
    }
    __syncthreads();
  }
  float bv[3];
#pragma unroll
  for (int ni = 0; ni < 3; ni++) bv[ni] = bias[n0 + wn + ni * 16 + l15];
#pragma unroll
  for (int mi = 0; mi < 2; mi++)
#pragma unroll
    for (int ni = 0; ni < 3; ni++)
#pragma unroll
      for (int r = 0; r < 4; r++) {
        int grow = m0 + wm + mi * 16 + quad * 4 + r;
        int gcol = n0 + wn + ni * 16 + l15;
        out[(size_t)grow * CDIM + gcol] = acc[mi * 3 + ni][r] + bv[ni];
      }
}

extern "C" void kernel_launch(void* const* d_in, const int* in_sizes, int n_in,
                              void* d_out, int out_size, void* d_ws, size_t ws_size,
                              hipStream_t stream) {
  const float* xq = (const float*)d_in[0];
  const float* xk = (const float*)d_in[1];
  const float* xv = (const float*)d_in[2];
  const float* wq = (const float*)d_in[3];
  const float* wk = (const float*)d_in[4];
  const float* wv = (const float*)d_in[5];
  const float* wp = (const float*)d_in[6];
  const float* bp = (const float*)d_in[7];
  float* out = (float*)d_out;

  char* p = (char*)d_ws;
  unsigned short* Xq = (unsigned short*)p; p += (size_t)XEL * 2;
  unsigned short* Xk = (unsigned short*)p; p += (size_t)XEL * 2;
  unsigned short* Xv = (unsigned short*)p; p += (size_t)XEL * 2;
  unsigned short* Wq = (unsigned short*)p; p += (size_t)WEL * 2;
  unsigned short* Wk = (unsigned short*)p; p += (size_t)WEL * 2;
  unsigned short* Wv = (unsigned short*)p; p += (size_t)WEL * 2;
  unsigned short* Wp = (unsigned short*)p; p += (size_t)WEL * 2;
  unsigned short* Qb = (unsigned short*)p; p += (size_t)XEL * 2;
  unsigned short* Kb = (unsigned short*)p; p += (size_t)XEL * 2;
  unsigned short* Vb = (unsigned short*)p; p += (size_t)XEL * 2;
  unsigned short* Cx = (unsigned short*)p; p += (size_t)XEL * 2;

  cast_all<<<(3 * X8 + 4 * W8) / 256, 256, 0, stream>>>(
      xq, xk, xv, wq, wk, wv, wp, Xq, Xk, Xv, Wq, Wk, Wv, Wp);

  gemm_qkv<<<768, 256, 0, stream>>>(
      Xq, Xk, Xv, Wq, Wk, Wv, Qb, Kb, Vb);

  attn_kernel<<<768, 256, 0, stream>>>(Qb, Kb, Vb, Cx);

  gemm_out<<<512, 256, 0, stream>>>(Cx, Wp, bp, out);
}

// Round 6
// 173.461 us; speedup vs baseline: 1.1747x; 1.0727x over previous
//
#include <hip/hip_runtime.h>
#include <hip/hip_bf16.h>

// Attention: xq/xk/xv [2,2048,768] f32, W* [768,768] f32 ([out,in]), bp [768] f32.
// Pipeline: fused cast->bf16, fused QKV NT-GEMM (scale*log2e folded into Q; V
// computed TRANSPOSED via swapped operands; XCD-swizzled blocks), flash attention
// (r14 structure: r13 32x32 MFMA in-register P + OVERLAP SCHEDULE -- single
// LDS buffer per half; per tile: frag reads -> lgkm0+schedbar+barrier ->
// stage(t+1) into same buffer -> register-only compute (hides L2 latency) ->
// vmcnt0+barrier. Same for both GEMMs (2-phase overlap).),
// output NT-GEMM + bias (64x96 tiles, BK=128, f32 out). LDS XOR-swizzled.

#define NSEQ 2048
#define CDIM 768
#define NH   12
#define HD   64
#define MTOT 4096            // B*NSEQ
#define XEL  (MTOT*CDIM)     // 3145728
#define WEL  (CDIM*CDIM)     // 589824
#define X8   (XEL/8)         // 393216
#define W8   (WEL/8)         // 73728
#define QSCALE 0.18033688011112042f   // 0.125 * log2(e); scores consumed by exp2

typedef __attribute__((ext_vector_type(8))) short bf16x8;
typedef __attribute__((ext_vector_type(4))) float floatx4;
typedef __attribute__((ext_vector_type(16))) float floatx16;
typedef __attribute__((ext_vector_type(4))) unsigned int uintx4;

// scalar f32->bf16, round-half-up (2 VALU)
static __device__ __forceinline__ unsigned short f2bf(float f) {
  union { float f; unsigned int u; } v; v.f = f;
  return (unsigned short)((v.u + 0x8000u) >> 16);
}
// packed pair f32->bf16x2, round-half-up: 2 v_add + 1 v_perm
static __device__ __forceinline__ unsigned pk2bf(float a, float b) {
  unsigned ua = __float_as_uint(a) + 0x8000u;
  unsigned ub = __float_as_uint(b) + 0x8000u;
  return __builtin_amdgcn_perm(ub, ua, 0x07060302);  // {hi16(b), hi16(a)}
}

static __device__ __forceinline__ void lds16(const void* g, void* l) {
  __builtin_amdgcn_global_load_lds(
      (const __attribute__((address_space(1))) unsigned int*)g,
      (__attribute__((address_space(3))) unsigned int*)l, 16, 0, 0);
}

// fences for the overlap schedule
#define LGKM0_SB()  do { asm volatile("s_waitcnt lgkmcnt(0)" ::: "memory"); \
                         __builtin_amdgcn_sched_barrier(0); } while (0)
#define VMCNT0()    asm volatile("s_waitcnt vmcnt(0)" ::: "memory")
#define BARRIER()   __builtin_amdgcn_s_barrier()
#define SB0()       __builtin_amdgcn_sched_barrier(0)

// ---------------- fused cast f32 -> bf16 (all 7 tensors, one launch) ----------
__global__ __launch_bounds__(256) void cast_all(
    const float* __restrict__ xq, const float* __restrict__ xk,
    const float* __restrict__ xv, const float* __restrict__ wq,
    const float* __restrict__ wk, const float* __restrict__ wv,
    const float* __restrict__ wp,
    unsigned short* __restrict__ Xq, unsigned short* __restrict__ Xk,
    unsigned short* __restrict__ Xv, unsigned short* __restrict__ Wq,
    unsigned short* __restrict__ Wk, unsigned short* __restrict__ Wv,
    unsigned short* __restrict__ Wp) {
  int i = blockIdx.x * 256 + threadIdx.x;
  const float* s; unsigned short* d; int off;
  if (i < 3 * X8) {
    int t = i / X8; off = i - t * X8;
    s = (t == 0) ? xq : (t == 1) ? xk : xv;
    d = (t == 0) ? Xq : (t == 1) ? Xk : Xv;
  } else {
    int j = i - 3 * X8; int t = j / W8; off = j - t * W8;
    s = (t == 0) ? wq : (t == 1) ? wk : (t == 2) ? wv : wp;
    d = (t == 0) ? Wq : (t == 1) ? Wk : (t == 2) ? Wv : Wp;
  }
  const float4* sp = (const float4*)s + (size_t)off * 2;
  float4 a = sp[0], b = sp[1];
  uint4 o;
  o.x = pk2bf(a.x, a.y); o.y = pk2bf(a.z, a.w);
  o.z = pk2bf(b.x, b.y); o.w = pk2bf(b.z, b.w);
  *(uint4*)(d + (size_t)off * 8) = o;
}

// ---------------- fused QKV NT-GEMM: 768 blocks, XCD-swizzled ----------------
// r14: 2-phase overlap -- frag reads, readers-barrier, stage(k0+64) into the
// same buffer, MFMA (overlaps staging latency), vmcnt0+barrier.
__global__ __launch_bounds__(256) void gemm_qkv(
    const unsigned short* __restrict__ Xq, const unsigned short* __restrict__ Xk,
    const unsigned short* __restrict__ Xv, const unsigned short* __restrict__ Wq,
    const unsigned short* __restrict__ Wk, const unsigned short* __restrict__ Wv,
    unsigned short* __restrict__ Qo, unsigned short* __restrict__ Ko,
    unsigned short* __restrict__ Vo) {
  int i0 = blockIdx.x;
  int mg = i0 & 7; int t0 = i0 >> 3;       // t0 in [0,96)
  int z = t0 % 3; int u = t0 / 3;          // u in [0,32)
  int xn = u & 7, ysub = u >> 3;           // 8 n-tiles x 4 m-subtiles
  int y = mg * 4 + ysub;                   // m-tile in [0,32)
  const unsigned short* A; const unsigned short* B; int am0, bn0, RA;
  if (z == 0)      { A = Xq; B = Wq; am0 = y * 128; bn0 = xn * 96; RA = 128; }
  else if (z == 1) { A = Xk; B = Wk; am0 = y * 128; bn0 = xn * 96; RA = 128; }
  else             { A = Wv; B = Xv; am0 = xn * 96; bn0 = y * 128; RA = 96; }
  __shared__ __align__(16) unsigned short S[224 * 64];
  int tid = threadIdx.x, lane = tid & 63, wave = tid >> 6;
  int quad = lane >> 4, l15 = lane & 15, l7 = l15 & 7;

  const unsigned short* gptr[7]; int ldo[7];
#pragma unroll
  for (int i = 0; i < 7; i++) {
    int idx = i * 256 + tid;
    int row = idx >> 3, c = (idx & 7) ^ (row & 7);
    gptr[i] = (row < RA ? A + (size_t)(am0 + row) * CDIM
                        : B + (size_t)(bn0 + row - RA) * CDIM) + c * 8;
    ldo[i] = idx * 8;
  }
  floatx4 acc[12];
#pragma unroll
  for (int i = 0; i < 12; i++) acc[i] = (floatx4){0.f, 0.f, 0.f, 0.f};

  // prologue: stage k0=0
#pragma unroll
  for (int i = 0; i < 7; i++) lds16(gptr[i], &S[ldo[i]]);
  VMCNT0();
  BARRIER();

  if (z < 2) {
    int wm = (wave >> 1) * 64, wn = (wave & 1) * 48;
    for (int k0 = 0; k0 < CDIM; k0 += 64) {
      bf16x8 af[2][4], bfr[2][3];
#pragma unroll
      for (int ks = 0; ks < 2; ks++) {
        int csw = ((ks * 4 + quad) ^ l7) * 8;
#pragma unroll
        for (int i = 0; i < 4; i++)
          af[ks][i] = *(const bf16x8*)&S[(wm + i * 16 + l15) * 64 + csw];
#pragma unroll
        for (int j = 0; j < 3; j++)
          bfr[ks][j] = *(const bf16x8*)&S[(128 + wn + j * 16 + l15) * 64 + csw];
      }
      LGKM0_SB();
      BARRIER();
      if (k0 + 64 < CDIM) {
#pragma unroll
        for (int i = 0; i < 7; i++) lds16(gptr[i] + k0 + 64, &S[ldo[i]]);
      }
      SB0();
#pragma unroll
      for (int ks = 0; ks < 2; ks++)
#pragma unroll
        for (int mi = 0; mi < 4; mi++)
#pragma unroll
          for (int ni = 0; ni < 3; ni++)
            acc[mi * 3 + ni] = __builtin_amdgcn_mfma_f32_16x16x32_bf16(
                af[ks][mi], bfr[ks][ni], acc[mi * 3 + ni], 0, 0, 0);
      VMCNT0();
      BARRIER();
    }
#pragma unroll
    for (int mi = 0; mi < 4; mi++)
#pragma unroll
      for (int ni = 0; ni < 3; ni++)
#pragma unroll
        for (int r = 0; r < 4; r++) {
          int grow = am0 + wm + mi * 16 + quad * 4 + r;
          int gcol = bn0 + wn + ni * 16 + l15;
          float v = acc[mi * 3 + ni][r];
          int b = grow >> 11, nq = grow & 2047, h = gcol >> 6, dd = gcol & 63;
          if (z == 0)
            Qo[((size_t)(b * NH + h) * NSEQ + nq) * HD + dd] = f2bf(v * QSCALE);
          else
            Ko[((size_t)(b * NH + h) * NSEQ + nq) * HD + dd] = f2bf(v);
        }
  } else {
    int wm = (wave & 1) * 48, wn = (wave >> 1) * 64;
    for (int k0 = 0; k0 < CDIM; k0 += 64) {
      bf16x8 af[2][3], bfr[2][4];
#pragma unroll
      for (int ks = 0; ks < 2; ks++) {
        int csw = ((ks * 4 + quad) ^ l7) * 8;
#pragma unroll
        for (int i = 0; i < 3; i++)
          af[ks][i] = *(const bf16x8*)&S[(wm + i * 16 + l15) * 64 + csw];
#pragma unroll
        for (int j = 0; j < 4; j++)
          bfr[ks][j] = *(const bf16x8*)&S[(96 + wn + j * 16 + l15) * 64 + csw];
      }
      LGKM0_SB();
      BARRIER();
      if (k0 + 64 < CDIM) {
#pragma unroll
        for (int i = 0; i < 7; i++) lds16(gptr[i] + k0 + 64, &S[ldo[i]]);
      }
      SB0();
#pragma unroll
      for (int ks = 0; ks < 2; ks++)
#pragma unroll
        for (int mi = 0; mi < 3; mi++)
#pragma unroll
          for (int ni = 0; ni < 4; ni++)
            acc[mi * 4 + ni] = __builtin_amdgcn_mfma_f32_16x16x32_bf16(
                af[ks][mi], bfr[ks][ni], acc[mi * 4 + ni], 0, 0, 0);
      VMCNT0();
      BARRIER();
    }
#pragma unroll
    for (int mi = 0; mi < 3; mi++)
#pragma unroll
      for (int ni = 0; ni < 4; ni++)
#pragma unroll
        for (int r = 0; r < 4; r++) {
          int o = am0 + wm + mi * 16 + quad * 4 + r;
          int mgl = bn0 + wn + ni * 16 + l15;
          int b = mgl >> 11, nq = mgl & 2047;
          Vo[((size_t)b * CDIM + o) * NSEQ + nq] = f2bf(acc[mi * 4 + ni][r]);
        }
  }
}

// ---------------- flash attention: r14 = r13 + overlap schedule --------------
// Q,K: [24][2048][64] bf16 (Q pre-scaled); Vt: [24][64][2048] bf16.
// ctx: [4096][768] bf16. 768 blocks x 256 thr = 4 waves:
//   wave = (half<<1)|qsub: qsub selects 32 q-rows, half selects kv half (1024).
// Single 8KB K + 8KB V buffer per half. Per tile: 16 frag ds_read -> lgkm0 +
// sched_barrier + s_barrier (all readers done) -> stage tile t+1 into the SAME
// buffer -> register-only compute (QK 32x32 MFMA, exp2, pack, permlane, PV)
// hides the staging L2 latency -> vmcnt0 + s_barrier (stage visible).
// P never touches LDS (r13); l = VALU tree + one permlane swap.
// Max-free softmax => halves combine exactly through LDS (swizzled Obuf).
__global__ __launch_bounds__(256, 3) void attn_kernel(
    const unsigned short* __restrict__ Q, const unsigned short* __restrict__ K,
    const unsigned short* __restrict__ Vt, unsigned short* __restrict__ ctx) {
  int i0 = blockIdx.x;
  int xcd = i0 & 7; int t0 = i0 >> 3;
  int bh = xcd * 3 + (t0 >> 5);
  int qt = t0 & 31;
  int tid = threadIdx.x, lane = tid & 63, wave = tid >> 6;
  int half = wave >> 1, qsub = wave & 1;
  int l31 = lane & 31, hi = lane >> 5;
  __shared__ __align__(16) unsigned short Ks[2][64 * 64];
  __shared__ __align__(16) unsigned short Vs[2][64 * 64];
  __shared__ float Lbuf[64];

  const unsigned short* Qg = Q + ((size_t)bh * NSEQ + qt * 64 + qsub * 32) * HD;
  const unsigned short* Kg = K + ((size_t)bh * NSEQ + half * 1024) * HD;
  const unsigned short* Vg = Vt + (size_t)bh * HD * NSEQ + half * 1024;

  // Q fragments (B-operand): lane holds Q[q=l31][d = dchunk*16 + hi*8 + j]
  bf16x8 qf[4];
#pragma unroll
  for (int dc = 0; dc < 4; dc++)
    qf[dc] = *(const bf16x8*)(Qg + l31 * HD + dc * 16 + hi * 8);

  // K/V staging: each half's 128 threads stage 8KB K + 8KB V
  int tid2 = tid & 127;
  int kgo[4], vgo[4], ldst[4];
#pragma unroll
  for (int i = 0; i < 4; i++) {
    int idx = i * 128 + tid2;
    int R = idx >> 3, c = (idx & 7) ^ (R & 7);
    kgo[i] = R * HD + c * 8;
    vgo[i] = R * NSEQ + c * 8;
    ldst[i] = idx * 8;
  }
  unsigned short* Ksh = Ks[half];
  unsigned short* Vsh = Vs[half];

  floatx16 o[2];
#pragma unroll
  for (int dt = 0; dt < 2; dt++) o[dt] = (floatx16)(0.f);
  float l_acc = 0.f;

  // prologue: stage tile 0
#pragma unroll
  for (int i = 0; i < 4; i++) {
    lds16(Kg + kgo[i], &Ksh[ldst[i]]);
    lds16(Vg + vgo[i], &Vsh[ldst[i]]);
  }
  VMCNT0();
  BARRIER();

  for (int t = 0; t < 16; t++) {
    // (a) fragment reads of tile t
    // K (A-operand): row kv = kb*32 + l31, k = dc*16 + hi*8 + j
    bf16x8 kf[2][4];
#pragma unroll
    for (int kb = 0; kb < 2; kb++)
#pragma unroll
      for (int dc = 0; dc < 4; dc++) {
        int R = kb * 32 + l31, c = dc * 2 + hi;
        kf[kb][dc] = *(const bf16x8*)&Ksh[R * 64 + ((c ^ (R & 7)) * 8)];
      }
    // V (A-operand): row d = dt*32 + l31, k(kv) = j*8-chunks
    bf16x8 vf[2][4];
#pragma unroll
    for (int dt = 0; dt < 2; dt++)
#pragma unroll
      for (int j = 0; j < 4; j++) {
        int R = dt * 32 + l31, c = j * 2 + hi;
        vf[dt][j] = *(const bf16x8*)&Vsh[R * 64 + ((c ^ (R & 7)) * 8)];
      }
    // (b) readers-done fence
    LGKM0_SB();
    BARRIER();
    // (c) stage tile t+1 into the same buffer (in flight across compute)
    if (t < 15) {
      int k0n = (t + 1) * 64;
#pragma unroll
      for (int i = 0; i < 4; i++) {
        lds16(Kg + (size_t)k0n * HD + kgo[i], &Ksh[ldst[i]]);
        lds16(Vg + k0n + vgo[i], &Vsh[ldst[i]]);
      }
    }
    SB0();
    // (d) register-only compute
#pragma unroll
    for (int kb = 0; kb < 2; kb++) {
      floatx16 st = (floatx16)(0.f);
#pragma unroll
      for (int dc = 0; dc < 4; dc++)
        st = __builtin_amdgcn_mfma_f32_32x32x16_bf16(kf[kb][dc], qf[dc], st, 0, 0, 0);
      // exp2 all 16 scores (max-free softmax)
      float p[16];
#pragma unroll
      for (int r = 0; r < 16; r++) p[r] = __builtin_exp2f(st[r]);
      // l: VALU tree sum of this lane's 16 values
      l_acc += ((p[0] + p[1]) + (p[2] + p[3])) + ((p[4] + p[5]) + (p[6] + p[7])) +
               (((p[8] + p[9]) + (p[10] + p[11])) + ((p[12] + p[13]) + (p[14] + p[15])));
      // pack pairs: w[i] = bf16{p[2i], p[2i+1]}
      unsigned w[8];
#pragma unroll
      for (int i = 0; i < 8; i++) w[i] = pk2bf(p[2 * i], p[2 * i + 1]);
      // permlane32_swap: build PV B-fragments (k = hi*8 + j within each kv16)
#pragma unroll
      for (int kvs = 0; kvs < 2; kvs++) {
        unsigned a0 = w[kvs * 4 + 0], b0 = w[kvs * 4 + 2];
        unsigned a1 = w[kvs * 4 + 1], b1 = w[kvs * 4 + 3];
        asm volatile("v_permlane32_swap_b32 %0, %1" : "+v"(a0), "+v"(b0));
        asm volatile("v_permlane32_swap_b32 %0, %1" : "+v"(a1), "+v"(b1));
        uintx4 pw; pw[0] = a0; pw[1] = a1; pw[2] = b0; pw[3] = b1;
        bf16x8 pb = *(bf16x8*)&pw;
#pragma unroll
        for (int dt = 0; dt < 2; dt++)
          o[dt] = __builtin_amdgcn_mfma_f32_32x32x16_bf16(
              vf[dt][kb * 2 + kvs], pb, o[dt], 0, 0, 0);
      }
    }
    // (e) stage-done fence (cheap: issued ~400 cyc ago)
    VMCNT0();
    BARRIER();
  }

  // complete l across lane halves: one permlane swap + add
  unsigned lu = __float_as_uint(l_acc), lv = __float_as_uint(l_acc);
  asm volatile("v_permlane32_swap_b32 %0, %1" : "+v"(lu), "+v"(lv));
  float lfull = __uint_as_float(lu) + __uint_as_float(lv);

  // in-block kv-half combine: half-1 -> LDS, half-0 adds + stores.
  // Obuf chunks XOR-swizzled by q (linear [64q][64d] f32 would be 32-way).
  float* Obuf = (float*)&Ks[0][0];   // 64q x 64d f32 = 16 KB (== Ks)
  int q = qsub * 32 + l31;
  if (half == 1) {
#pragma unroll
    for (int dt = 0; dt < 2; dt++)
#pragma unroll
      for (int rq = 0; rq < 4; rq++) {
        int ch = (dt * 8 + rq * 2 + hi) ^ (l31 & 15);
        floatx4 v4 = {o[dt][rq * 4 + 0], o[dt][rq * 4 + 1],
                      o[dt][rq * 4 + 2], o[dt][rq * 4 + 3]};
        *(floatx4*)&Obuf[q * 64 + ch * 4] = v4;
      }
    if (lane < 32) Lbuf[qsub * 32 + lane] = lfull;
  }
  __syncthreads();
  if (half == 0) {
    int b = bh / NH, h = bh - b * NH;
    float inv = 1.f / (lfull + Lbuf[q]);
    int qrow = qt * 64 + q;
#pragma unroll
    for (int dt = 0; dt < 2; dt++)
#pragma unroll
      for (int rq = 0; rq < 4; rq++) {
        int ch = (dt * 8 + rq * 2 + hi) ^ (l31 & 15);
        floatx4 ob = *(floatx4*)&Obuf[q * 64 + ch * 4];
        float v0 = (o[dt][rq * 4 + 0] + ob[0]) * inv;
        float v1 = (o[dt][rq * 4 + 1] + ob[1]) * inv;
        float v2 = (o[dt][rq * 4 + 2] + ob[2]) * inv;
        float v3 = (o[dt][rq * 4 + 3] + ob[3]) * inv;
        size_t gbase = (size_t)(b * NSEQ + qrow) * CDIM + h * HD +
                       dt * 32 + rq * 8 + hi * 4;
        *(uint2*)&ctx[gbase] = make_uint2(pk2bf(v0, v1), pk2bf(v2, v3));
      }
  }
}

// ------------- output NT-GEMM + bias, 64x96 tiles, BK=128, XCD-swizzled ------
// r14: 2-phase overlap schedule (same as gemm_qkv).
__global__ __launch_bounds__(256) void gemm_out(
    const unsigned short* __restrict__ A, const unsigned short* __restrict__ B,
    const float* __restrict__ bias, float* __restrict__ out) {
  int i0 = blockIdx.x;                  // 512 blocks = 2/CU
  int mg = i0 & 7; int t0 = i0 >> 3;    // t0 in [0,64)
  int n0 = (t0 & 7) * 96;
  int m0 = (mg * 8 + (t0 >> 3)) * 64;
  __shared__ __align__(16) unsigned short S[160 * 128];  // A rows 0..63, B rows 64..159
  int tid = threadIdx.x, lane = tid & 63, wave = tid >> 6;
  int quad = lane >> 4, l15 = lane & 15, l7 = l15 & 7;
  int wm = (wave >> 1) * 32, wn = (wave & 1) * 48;
  floatx4 acc[6];
#pragma unroll
  for (int i = 0; i < 6; i++) acc[i] = (floatx4){0.f, 0.f, 0.f, 0.f};

  int sro[10]; const unsigned short* sgp[10];
#pragma unroll
  for (int i = 0; i < 10; i++) {       // 160 rows x 16 chunks = 2560 = 10*256
    int idx = i * 256 + tid;
    int R = idx >> 4, c4 = idx & 15;
    int cs = (c4 & 8) | ((c4 & 7) ^ (R & 7));
    sgp[i] = ((R < 64) ? A + (size_t)(m0 + R) * CDIM
                       : B + (size_t)(n0 + R - 64) * CDIM) + cs * 8;
    sro[i] = idx * 8;
  }
  // prologue: stage k0=0
#pragma unroll
  for (int i = 0; i < 10; i++) lds16(sgp[i], &S[sro[i]]);
  VMCNT0();
  BARRIER();

  for (int k0 = 0; k0 < CDIM; k0 += 128) {
    bf16x8 af[4][2], bfr[4][3];
#pragma unroll
    for (int ks = 0; ks < 4; ks++) {
      int c = ks * 4 + quad;
      int csw = ((c & 8) | ((c & 7) ^ l7)) * 8;
#pragma unroll
      for (int i = 0; i < 2; i++)
        af[ks][i] = *(const bf16x8*)&S[(wm + i * 16 + l15) * 128 + csw];
#pragma unroll
      for (int j = 0; j < 3; j++)
        bfr[ks][j] = *(const bf16x8*)&S[(64 + wn + j * 16 + l15) * 128 + csw];
    }
    LGKM0_SB();
    BARRIER();
    if (k0 + 128 < CDIM) {
#pragma unroll
      for (int i = 0; i < 10; i++) lds16(sgp[i] + k0 + 128, &S[sro[i]]);
    }
    SB0();
#pragma unroll
    for (int ks = 0; ks < 4; ks++)
#pragma unroll
      for (int mi = 0; mi < 2; mi++)
#pragma unroll
        for (int ni = 0; ni < 3; ni++)
          acc[mi * 3 + ni] = __builtin_amdgcn_mfma_f32_16x16x32_bf16(
              af[ks][mi], bfr[ks][ni], acc[mi * 3 + ni], 0, 0, 0);
    VMCNT0();
    BARRIER();
  }
  float bv[3];
#pragma unroll
  for (int ni = 0; ni < 3; ni++) bv[ni] = bias[n0 + wn + ni * 16 + l15];
#pragma unroll
  for (int mi = 0; mi < 2; mi++)
#pragma unroll
    for (int ni = 0; ni < 3; ni++)
#pragma unroll
      for (int r = 0; r < 4; r++) {
        int grow = m0 + wm + mi * 16 + quad * 4 + r;
        int gcol = n0 + wn + ni * 16 + l15;
        out[(size_t)grow * CDIM + gcol] = acc[mi * 3 + ni][r] + bv[ni];
      }
}

extern "C" void kernel_launch(void* const* d_in, const int* in_sizes, int n_in,
                              void* d_out, int out_size, void* d_ws, size_t ws_size,
                              hipStream_t stream) {
  const float* xq = (const float*)d_in[0];
  const float* xk = (const float*)d_in[1];
  const float* xv = (const float*)d_in[2];
  const float* wq = (const float*)d_in[3];
  const float* wk = (const float*)d_in[4];
  const float* wv = (const float*)d_in[5];
  const float* wp = (const float*)d_in[6];
  const float* bp = (const float*)d_in[7];
  float* out = (float*)d_out;

  char* p = (char*)d_ws;
  unsigned short* Xq = (unsigned short*)p; p += (size_t)XEL * 2;
  unsigned short* Xk = (unsigned short*)p; p += (size_t)XEL * 2;
  unsigned short* Xv = (unsigned short*)p; p += (size_t)XEL * 2;
  unsigned short* Wq = (unsigned short*)p; p += (size_t)WEL * 2;
  unsigned short* Wk = (unsigned short*)p; p += (size_t)WEL * 2;
  unsigned short* Wv = (unsigned short*)p; p += (size_t)WEL * 2;
  unsigned short* Wp = (unsigned short*)p; p += (size_t)WEL * 2;
  unsigned short* Qb = (unsigned short*)p; p += (size_t)XEL * 2;
  unsigned short* Kb = (unsigned short*)p; p += (size_t)XEL * 2;
  unsigned short* Vb = (unsigned short*)p; p += (size_t)XEL * 2;
  unsigned short* Cx = (unsigned short*)p; p += (size_t)XEL * 2;

  cast_all<<<(3 * X8 + 4 * W8) / 256, 256, 0, stream>>>(
      xq, xk, xv, wq, wk, wv, wp, Xq, Xk, Xv, Wq, Wk, Wv, Wp);

  gemm_qkv<<<768, 256, 0, stream>>>(
      Xq, Xk, Xv, Wq, Wk, Wv, Qb, Kb, Vb);

  attn_kernel<<<768, 256, 0, stream>>>(Qb, Kb, Vb, Cx);

  gemm_out<<<512, 256, 0, stream>>>(Cx, Wp, bp, out);
}